// Round 7
// baseline (224.662 us; speedup 1.0000x reference)
//
#include <hip/hip_runtime.h>
#include <hip/hip_bf16.h>
#include <stdint.h>

#define NN 100000
#define NE 1600000
#define HD 128
#define NG 500
#define NPG 200

#define NBK 782      // node buckets of 128: ceil(NN/128)
#define NBLK 128     // scatter blocks
#define CHUNK 12500  // edges per scatter block (NBLK*CHUNK == NE)

typedef __attribute__((ext_vector_type(8))) short short8v;
typedef __attribute__((ext_vector_type(4))) float float4v;
typedef __attribute__((ext_vector_type(2))) float float2v;

// ---------- bf16 helpers (bit-level, RNE) ----------
__device__ __forceinline__ float bflo(unsigned int u) { return __uint_as_float(u << 16); }
__device__ __forceinline__ float bfhi(unsigned int u) { return __uint_as_float(u & 0xffff0000u); }
__device__ __forceinline__ unsigned int packbf(float a, float b) {
  unsigned int ua = __float_as_uint(a), ub = __float_as_uint(b);
  ua += 0x7fffu + ((ua >> 16) & 1u);
  ub += 0x7fffu + ((ub >> 16) & 1u);
  return (ua >> 16) | (ub & 0xffff0000u);
}

// ---------- edge dtype helper (int32 vs int64 detected in-kernel) ----------
__device__ __forceinline__ int edge_at(const void* p, int is64, int idx) {
  return is64 ? (int)((const long long*)p)[idx] : ((const int*)p)[idx];
}

// all 256 threads participate; sf is one LDS int
__device__ __forceinline__ int detect_is64(const void* edges, int tid, int* sf) {
  if (tid == 0) *sf = 0;
  __syncthreads();
  const unsigned int* p = (const unsigned int*)edges;
  unsigned int e = p[2 * tid], o = p[2 * tid + 1];
  unsigned int m = (e ? 1u : 0u) | (o ? 2u : 0u);
  if (m) atomicOr(sf, (int)m);
  __syncthreads();
  int v = *sf;
  return ((v & 2) == 0) && (v & 1);  // all-odd-zero & some-even-nonzero => int64
}

// ---------- counting sort pass 1: per-(bucket,block) histogram via LDS ----------
__global__ __launch_bounds__(256) void k_hist1(const void* __restrict__ edges,
                                               int* __restrict__ hist) {
  __shared__ int lh[1024];
  __shared__ int sf;
  int tid = threadIdx.x, blk = blockIdx.x;
  int f = detect_is64(edges, tid, &sf);
  for (int i = tid; i < NBK; i += 256) lh[i] = 0;
  __syncthreads();
  int e0 = blk * CHUNK, e1 = e0 + CHUNK;
  if (e1 > NE) e1 = NE;
  for (int e = e0 + tid; e < e1; e += 256) {
    int d = edge_at(edges, f, NE + e);
    atomicAdd(&lh[d >> 7], 1);
  }
  __syncthreads();
  for (int i = tid; i < NBK; i += 256) hist[i * NBLK + blk] = lh[i];
}

// ---------- generic exclusive scan (3 kernels) ----------
__global__ void k_scan_block(const int* __restrict__ in, int* __restrict__ outv,
                             int* __restrict__ bsums, int n) {
  __shared__ int s[256];
  int tid = threadIdx.x;
  int i = blockIdx.x * 256 + tid;
  int v = (i < n) ? in[i] : 0;
  s[tid] = v;
  __syncthreads();
  for (int off = 1; off < 256; off <<= 1) {
    int t = (tid >= off) ? s[tid - off] : 0;
    __syncthreads();
    s[tid] += t;
    __syncthreads();
  }
  if (i < n) outv[i] = s[tid] - v;
  if (tid == 255) bsums[blockIdx.x] = s[255];
}

__global__ void k_scan_sums(int* __restrict__ bsums, int nb) {
  __shared__ int s[512];
  int tid = threadIdx.x;
  int v = (tid < nb) ? bsums[tid] : 0;
  s[tid] = v;
  __syncthreads();
  for (int off = 1; off < 512; off <<= 1) {
    int t = (tid >= off) ? s[tid - off] : 0;
    __syncthreads();
    s[tid] += t;
    __syncthreads();
  }
  if (tid < nb) bsums[tid] = s[tid] - v;
}

__global__ void k_scan_add(int* __restrict__ outv, const int* __restrict__ bsums, int n) {
  int i = blockIdx.x * blockDim.x + threadIdx.x;
  if (i < n) outv[i] += bsums[i >> 8];
}

// ---------- counting sort pass 2: scatter records to exact slots ----------
// record = (dst&127)<<17 | src
__global__ __launch_bounds__(256) void k_scatter(const void* __restrict__ edges,
                                                 const int* __restrict__ histS,
                                                 unsigned int* __restrict__ sorted) {
  __shared__ int base[1024];
  __shared__ int sf;
  int tid = threadIdx.x, blk = blockIdx.x;
  int f = detect_is64(edges, tid, &sf);
  for (int i = tid; i < NBK; i += 256) base[i] = histS[i * NBLK + blk];
  __syncthreads();
  int e0 = blk * CHUNK, e1 = e0 + CHUNK;
  if (e1 > NE) e1 = NE;
  for (int e = e0 + tid; e < e1; e += 256) {
    int s = edge_at(edges, f, e);
    int d = edge_at(edges, f, NE + e);
    int pos = atomicAdd(&base[d >> 7], 1);
    sorted[pos] = ((unsigned)(d & 127) << 17) | (unsigned)s;
  }
}

// ---------- pass B: bucket records -> node-ordered CSR + rowstart + dinv ----------
__global__ __launch_bounds__(256) void k_passB2(const unsigned int* __restrict__ sorted,
                                                const int* __restrict__ histS,
                                                int* __restrict__ rowstart,
                                                float* __restrict__ dinv,
                                                int* __restrict__ csr) {
  __shared__ int cnt[128];
  __shared__ int sc[256];
  __shared__ int fill[128];
  __shared__ int stage[4096];
  int b = blockIdx.x, tid = threadIdx.x;
  int ebase = histS[b * NBLK];
  int eend = (b + 1 < NBK) ? histS[(b + 1) * NBLK] : NE;
  int ne = eend - ebase;
  if (tid < 128) { cnt[tid] = 0; fill[tid] = 0; }
  __syncthreads();
  for (int i = tid; i < ne; i += 256) {
    unsigned int r = sorted[ebase + i];
    atomicAdd(&cnt[r >> 17], 1);
  }
  __syncthreads();
  int v = (tid < 128) ? cnt[tid] : 0;
  sc[tid] = v;
  __syncthreads();
  for (int off = 1; off < 256; off <<= 1) {
    int t = (tid >= off) ? sc[tid - off] : 0;
    __syncthreads();
    sc[tid] += t;
    __syncthreads();
  }
  int node = (b << 7) + tid;
  if (tid < 128 && node < NN) {
    rowstart[node] = ebase + sc[tid] - cnt[tid];
    dinv[node] = rsqrtf((float)(cnt[tid] + 1));  // +1 self loop
  }
  if (b == NBK - 1 && tid == 0) rowstart[NN] = NE;
  __syncthreads();
  for (int i = tid; i < ne; i += 256) {
    unsigned int r = sorted[ebase + i];
    int ld = (int)(r >> 17);
    int pos = atomicAdd(&fill[ld], 1);
    stage[sc[ld] - cnt[ld] + pos] = (int)(r & 0x1FFFFu);
  }
  __syncthreads();
  for (int i = tid; i < ne; i += 256) csr[ebase + i] = stage[i];
}

// ---------- degree-balanced order: counting sort by degree within each graph ----------
__global__ __launch_bounds__(256) void k_order(const int* __restrict__ rowstart,
                                               int* __restrict__ order) {
  __shared__ int h[128];
  __shared__ int sc[256];
  __shared__ int fill[128];
  __shared__ int degs[256];
  int g = blockIdx.x, tid = threadIdx.x;
  if (tid < 128) { h[tid] = 0; fill[tid] = 0; }
  __syncthreads();
  if (tid < NPG) {
    int n = g * NPG + tid;
    int d = rowstart[n + 1] - rowstart[n];
    if (d > 127) d = 127;
    degs[tid] = d;
    atomicAdd(&h[d], 1);
  }
  __syncthreads();
  int v = (tid < 128) ? h[tid] : 0;
  sc[tid] = v;
  __syncthreads();
  for (int off = 1; off < 256; off <<= 1) {
    int t = (tid >= off) ? sc[tid - off] : 0;
    __syncthreads();
    sc[tid] += t;
    __syncthreads();
  }
  if (tid < NPG) {
    int d = degs[tid];
    int pos = sc[d] - h[d] + atomicAdd(&fill[d], 1);
    order[g * NPG + pos] = g * NPG + tid;
  }
}

// ---------- fp32 -> fp8 convert with prescale: xs8[v] = fp8(8 * dinv[v] * x[v]) ----------
__global__ void k_cvt8(const float4* __restrict__ in, uint2* __restrict__ out,
                       const float* __restrict__ dinv) {
  int i = blockIdx.x * 256 + threadIdx.x;  // 8-element group; node = i>>4
  float s = dinv[i >> 4] * 8.f;
  float4 a = in[(size_t)i * 2], b = in[(size_t)i * 2 + 1];
  int w0 = __builtin_amdgcn_cvt_pk_fp8_f32(a.x * s, a.y * s, 0, false);
  w0 = __builtin_amdgcn_cvt_pk_fp8_f32(a.z * s, a.w * s, w0, true);
  int w1 = __builtin_amdgcn_cvt_pk_fp8_f32(b.x * s, b.y * s, 0, false);
  w1 = __builtin_amdgcn_cvt_pk_fp8_f32(b.z * s, b.w * s, w1, true);
  out[i] = make_uint2((unsigned)w0, (unsigned)w1);
}

// ---------- W1 fp32 [128][128] -> bf16 transposed W1t[c][k] ----------
__global__ void k_cvtW(const float* __restrict__ W, unsigned int* __restrict__ Wt) {
  int i = blockIdx.x * 256 + threadIdx.x;  // 0..8191
  int c = i >> 6, kp = i & 63;
  float w0 = W[(size_t)(2 * kp) * 128 + c];
  float w1 = W[(size_t)(2 * kp + 1) * 128 + c];
  Wt[c * 64 + kp] = packbf(w0, w1);
}

// ---------- fp8 gather-aggregate core: 8 lanes/node, uint4 (16 fp8 ch)/lane ----------
__device__ __forceinline__ void accf16(float* a, uint4 v) {
  float2v f;
  f = __builtin_amdgcn_cvt_pk_f32_fp8((int)v.x, false); a[0] += f.x;  a[1] += f.y;
  f = __builtin_amdgcn_cvt_pk_f32_fp8((int)v.x, true);  a[2] += f.x;  a[3] += f.y;
  f = __builtin_amdgcn_cvt_pk_f32_fp8((int)v.y, false); a[4] += f.x;  a[5] += f.y;
  f = __builtin_amdgcn_cvt_pk_f32_fp8((int)v.y, true);  a[6] += f.x;  a[7] += f.y;
  f = __builtin_amdgcn_cvt_pk_f32_fp8((int)v.z, false); a[8] += f.x;  a[9] += f.y;
  f = __builtin_amdgcn_cvt_pk_f32_fp8((int)v.z, true);  a[10] += f.x; a[11] += f.y;
  f = __builtin_amdgcn_cvt_pk_f32_fp8((int)v.w, false); a[12] += f.x; a[13] += f.y;
  f = __builtin_amdgcn_cvt_pk_f32_fp8((int)v.w, true);  a[14] += f.x; a[15] += f.y;
}

#define AGG_CORE16(IN, NODE, L, A)                                               \
  float A[16];                                                                   \
  _Pragma("unroll") for (int j = 0; j < 16; ++j) A[j] = 0.f;                     \
  {                                                                              \
    uint4 sv = IN[(size_t)(NODE)*8 + (L)];                                       \
    accf16(A, sv);                                                               \
  }                                                                              \
  {                                                                              \
    int i = rowstart[NODE], end = rowstart[(NODE) + 1];                          \
    for (; i + 7 < end; i += 8) {                                                \
      int s0 = csr[i], s1 = csr[i + 1], s2 = csr[i + 2], s3 = csr[i + 3];        \
      int s4 = csr[i + 4], s5 = csr[i + 5], s6 = csr[i + 6], s7 = csr[i + 7];    \
      uint4 v0 = IN[(size_t)s0 * 8 + (L)];                                       \
      uint4 v1 = IN[(size_t)s1 * 8 + (L)];                                       \
      uint4 v2 = IN[(size_t)s2 * 8 + (L)];                                       \
      uint4 v3 = IN[(size_t)s3 * 8 + (L)];                                       \
      uint4 v4 = IN[(size_t)s4 * 8 + (L)];                                       \
      uint4 v5 = IN[(size_t)s5 * 8 + (L)];                                       \
      uint4 v6 = IN[(size_t)s6 * 8 + (L)];                                       \
      uint4 v7 = IN[(size_t)s7 * 8 + (L)];                                       \
      accf16(A, v0); accf16(A, v1); accf16(A, v2); accf16(A, v3);                \
      accf16(A, v4); accf16(A, v5); accf16(A, v6); accf16(A, v7);                \
    }                                                                            \
    for (; i + 3 < end; i += 4) {                                                \
      int s0 = csr[i], s1 = csr[i + 1], s2 = csr[i + 2], s3 = csr[i + 3];        \
      uint4 v0 = IN[(size_t)s0 * 8 + (L)];                                       \
      uint4 v1 = IN[(size_t)s1 * 8 + (L)];                                       \
      uint4 v2 = IN[(size_t)s2 * 8 + (L)];                                       \
      uint4 v3 = IN[(size_t)s3 * 8 + (L)];                                       \
      accf16(A, v0); accf16(A, v1); accf16(A, v2); accf16(A, v3);                \
    }                                                                            \
    for (; i < end; ++i) {                                                       \
      uint4 v0 = IN[(size_t)csr[i] * 8 + (L)];                                   \
      accf16(A, v0);                                                             \
    }                                                                            \
  }

// ---------- fused agg1 + GEMM1 (MFMA): h1s8[v] = fp8(16*dinv*relu(Agg(x)@W1+b1)) ----------
// Block = 32 nodes (degree-sorted) = one 32x128 A-tile. 4 waves x (1 row-tile x 4 col-tiles).
// Input xs8 = fp8(8*dinv*x) -> acc*(dinv/8) = Agg(x) row (true scale).
__global__ __launch_bounds__(256) void k_agg1g(const uint4* __restrict__ in,
                                               const unsigned int* __restrict__ W1t,
                                               const float* __restrict__ bias,
                                               uint4* __restrict__ out,
                                               const int* __restrict__ rowstart,
                                               const int* __restrict__ csr,
                                               const float* __restrict__ dinv,
                                               const int* __restrict__ order) {
  __shared__ uint4 At[32 * 16];   // bf16 A-tile, row r chunk s at At[r*16 + (s^(r&7))]
  __shared__ float Ot[32 * 128];  // f32 out-tile, elem (r,c) at byte r*512 + ((c*4)^((r&7)<<4))
  __shared__ float sdv[32];
  int tid = threadIdx.x;
  int nl = tid >> 3, l = tid & 7;  // node-local 0..31, lane 0..7 (16 ch each)
  int pos = blockIdx.x * 32 + nl;
  int node = order[pos];
  AGG_CORE16(in, node, l, a)
  float dv = dinv[node];
  if (l == 0) sdv[nl] = dv;
  {
    float ds = dv * 0.125f;  // undo the 8x input prescale
    uint4 c0, c1;
    c0.x = packbf(a[0] * ds, a[1] * ds);   c0.y = packbf(a[2] * ds, a[3] * ds);
    c0.z = packbf(a[4] * ds, a[5] * ds);   c0.w = packbf(a[6] * ds, a[7] * ds);
    c1.x = packbf(a[8] * ds, a[9] * ds);   c1.y = packbf(a[10] * ds, a[11] * ds);
    c1.z = packbf(a[12] * ds, a[13] * ds); c1.w = packbf(a[14] * ds, a[15] * ds);
    At[nl * 16 + ((2 * l) ^ (nl & 7))] = c0;
    At[nl * 16 + ((2 * l + 1) ^ (nl & 7))] = c1;
  }
  __syncthreads();

  // MFMA: wave w -> row-tile rt=w>>1, col-tiles {(w&1)*4 .. +3}
  int w = tid >> 6, lane = tid & 63;
  int m = lane & 15, g = lane >> 4;
  int rt = w >> 1, cb = (w & 1) * 4;
  int row = rt * 16 + m;
  float4v acc[4];
#pragma unroll
  for (int t = 0; t < 4; ++t) acc[t] = (float4v)0.f;
#pragma unroll
  for (int ks = 0; ks < 4; ++ks) {
    int slot = ks * 4 + g;
    short8v af = *(const short8v*)&At[row * 16 + (slot ^ (row & 7))];
#pragma unroll
    for (int t = 0; t < 4; ++t) {
      int c = (cb + t) * 16 + m;
      short8v bf = *(const short8v*)&W1t[c * 64 + ks * 16 + g * 4];
      acc[t] = __builtin_amdgcn_mfma_f32_16x16x32_bf16(af, bf, acc[t], 0, 0, 0);
    }
  }
  // epilogue: bias + relu + (16*dinv) prescale -> swizzled f32 tile
#pragma unroll
  for (int t = 0; t < 4; ++t) {
    int c = (cb + t) * 16 + m;
    float bl = bias[c];
#pragma unroll
    for (int j = 0; j < 4; ++j) {
      int r = rt * 16 + g * 4 + j;
      float v = fmaxf(acc[t][j] + bl, 0.f) * (sdv[r] * 16.f);
      *(float*)((char*)Ot + r * 512 + ((c * 4) ^ ((r & 7) << 4))) = v;
    }
  }
  __syncthreads();
  // readout: 8-lane group nl streams row nl (lane covers 16 ch = 64 B), packs fp8
  {
    int s = (nl & 7) << 4;
    const char* base = (const char*)Ot + nl * 512;
    float4 f0 = *(const float4*)(base + ((l * 64) ^ s));
    float4 f1 = *(const float4*)(base + ((l * 64 + 16) ^ s));
    float4 f2 = *(const float4*)(base + ((l * 64 + 32) ^ s));
    float4 f3 = *(const float4*)(base + ((l * 64 + 48) ^ s));
    int w0 = __builtin_amdgcn_cvt_pk_fp8_f32(f0.x, f0.y, 0, false);
    w0 = __builtin_amdgcn_cvt_pk_fp8_f32(f0.z, f0.w, w0, true);
    int w1 = __builtin_amdgcn_cvt_pk_fp8_f32(f1.x, f1.y, 0, false);
    w1 = __builtin_amdgcn_cvt_pk_fp8_f32(f1.z, f1.w, w1, true);
    int w2 = __builtin_amdgcn_cvt_pk_fp8_f32(f2.x, f2.y, 0, false);
    w2 = __builtin_amdgcn_cvt_pk_fp8_f32(f2.z, f2.w, w2, true);
    int w3 = __builtin_amdgcn_cvt_pk_fp8_f32(f3.x, f3.y, 0, false);
    w3 = __builtin_amdgcn_cvt_pk_fp8_f32(f3.z, f3.w, w3, true);
    uint4 o = make_uint4((unsigned)w0, (unsigned)w1, (unsigned)w2, (unsigned)w3);
    out[(size_t)node * 8 + l] = o;
  }
}

// agg2 + fused per-graph sum pool (32 degree-sorted nodes/block; block spans <=2 graphs)
__global__ __launch_bounds__(256) void k_agg2p(const uint4* __restrict__ in,
                                               float* __restrict__ poolsum,
                                               const int* __restrict__ rowstart,
                                               const int* __restrict__ csr,
                                               const float* __restrict__ dinv,
                                               const int* __restrict__ order) {
  __shared__ float sh[32][128];
  int tid = threadIdx.x;
  int nl = tid >> 3, l = tid & 7;
  int pos = blockIdx.x * 32 + nl;
  int node = order[pos];
  AGG_CORE16(in, node, l, a)
  float dv = dinv[node];
#pragma unroll
  for (int j = 0; j < 16; ++j) a[j] *= dv;
#pragma unroll
  for (int q = 0; q < 4; ++q)
    *(float4*)&sh[nl][l * 16 + q * 4] = make_float4(a[q * 4], a[q * 4 + 1], a[q * 4 + 2], a[q * 4 + 3]);
  __syncthreads();
  if (tid < 128) {
    int n0 = blockIdx.x * 32;
    int gA = n0 / NPG;
    int split = (gA + 1) * NPG - n0;  // positions [0,split) belong to gA
    if (split > 32) split = 32;
    float sA = 0.f, sB = 0.f;
#pragma unroll
    for (int n = 0; n < 32; ++n) {
      float v = sh[n][tid];
      if (n < split) sA += v; else sB += v;
    }
    atomicAdd(&poolsum[gA * 128 + tid], sA);
    if (split < 32) atomicAdd(&poolsum[(gA + 1) * 128 + tid], sB);
  }
}

// ---------- GEMM2 small-M: out[M x 128] = (A*ascale) @ W + bias, 8 rows/block ----------
__global__ __launch_bounds__(256) void k_gemm2s(const float* __restrict__ A,
                                                const float* __restrict__ W,
                                                const float* __restrict__ bias,
                                                float* __restrict__ out, int M, float ascale) {
  __shared__ float As[8][128];
  int tid = threadIdx.x;
  int row0 = blockIdx.x * 8;
  {
    int r = tid >> 5, c4 = (tid & 31) * 4;
    float4 v = make_float4(0.f, 0.f, 0.f, 0.f);
    if (row0 + r < M) v = *(const float4*)&A[(size_t)(row0 + r) * 128 + c4];
    *(float4*)&As[r][c4] = make_float4(v.x * ascale, v.y * ascale, v.z * ascale, v.w * ascale);
  }
  __syncthreads();
  int r = tid >> 5, c0 = (tid & 31) * 4;
  float acc0 = 0.f, acc1 = 0.f, acc2 = 0.f, acc3 = 0.f;
  for (int k = 0; k < 128; ++k) {
    float a = As[r][k];
    float4 wv = *(const float4*)&W[(size_t)k * 128 + c0];
    acc0 = fmaf(a, wv.x, acc0); acc1 = fmaf(a, wv.y, acc1);
    acc2 = fmaf(a, wv.z, acc2); acc3 = fmaf(a, wv.w, acc3);
  }
  if (row0 + r < M) {
    float4 o;
    o.x = acc0 + bias[c0]; o.y = acc1 + bias[c0 + 1];
    o.z = acc2 + bias[c0 + 2]; o.w = acc3 + bias[c0 + 3];
    *(float4*)&out[(size_t)(row0 + r) * 128 + c0] = o;
  }
}

extern "C" void kernel_launch(void* const* d_in, const int* in_sizes, int n_in,
                              void* d_out, int out_size, void* d_ws, size_t ws_size,
                              hipStream_t stream) {
  const float* x  = (const float*)d_in[0];
  const void* edges = d_in[1];
  const float* W1 = (const float*)d_in[3];
  const float* b1 = (const float*)d_in[4];
  const float* W2 = (const float*)d_in[5];
  const float* b2 = (const float*)d_in[6];
  float* out = (float*)d_out;

  // workspace layout (bytes), ~40.7 MB total
  char* ws = (char*)d_ws;
  float* poolsum  = (float*)(ws + 0);          // 256000  (zeroed)
  int*   hist     = (int*)(ws + 256000);       // 400384
  int*   histS    = (int*)(ws + 656384);       // 400384
  int*   bsums    = (int*)(ws + 1056768);      // 2048
  int*   rowstart = (int*)(ws + 1058816);      // 400016
  float* dinv     = (float*)(ws + 1458832);    // 400000
  int*   order    = (int*)(ws + 1858832);      // 400000
  unsigned int* W1t = (unsigned int*)(ws + 2258832);     // 32768 (bf16 W1^T)
  unsigned int* sorted = (unsigned int*)(ws + 2291600);  // 6.4 MB
  int*   csr      = (int*)(ws + 8691600);      // 6.4 MB
  void*  xs8      = (void*)(ws + 15091600);    // 12.8 MB  fp8(8*dinv*x)
  void*  h1s8     = (void*)(ws + 27891600);    // 12.8 MB  fp8(16*dinv*h1)

  hipMemsetAsync(poolsum, 0, 256000, stream);

  const int NH = NBK * NBLK;  // 100096 histogram entries

  k_hist1<<<NBLK, 256, 0, stream>>>(edges, hist);
  k_scan_block<<<(NH + 255) / 256, 256, 0, stream>>>(hist, histS, bsums, NH);
  k_scan_sums<<<1, 512, 0, stream>>>(bsums, (NH + 255) / 256);
  k_scan_add<<<(NH + 255) / 256, 256, 0, stream>>>(histS, bsums, NH);
  k_scatter<<<NBLK, 256, 0, stream>>>(edges, histS, sorted);
  k_passB2<<<NBK, 256, 0, stream>>>(sorted, histS, rowstart, dinv, csr);
  k_order<<<NG, 256, 0, stream>>>(rowstart, order);

  // xs8 = fp8(8*dinv*x); W1t = bf16(W1^T)
  k_cvt8<<<NN * HD / 8 / 256, 256, 0, stream>>>((const float4*)x, (uint2*)xs8, dinv);
  k_cvtW<<<32, 256, 0, stream>>>(W1, W1t);

  // conv1 fused: h1s8 = fp8( 16 * dinv * relu( Agg(x) @ W1 + b1 ) )
  k_agg1g<<<NN / 32, 256, 0, stream>>>((const uint4*)xs8, W1t, b1, (uint4*)h1s8,
                                       rowstart, csr, dinv, order);
  // conv2 fused with pool: poolsum = 16 * sum_graph( dinv*(h1s self+gather) )
  k_agg2p<<<NN / 32, 256, 0, stream>>>((const uint4*)h1s8, poolsum, rowstart, csr, dinv, order);
  // out = (poolsum/(200*16)) @ W2 + b2
  k_gemm2s<<<(NG + 7) / 8, 256, 0, stream>>>(poolsum, W2, b2, out, NG, 1.f / 3200.f);
}